// Round 8
// baseline (120.324 us; speedup 1.0000x reference)
//
#include <hip/hip_runtime.h>

typedef float f32x2 __attribute__((ext_vector_type(2)));
typedef float f32x4 __attribute__((ext_vector_type(4)));

#define PAD 3
#define HH 320
#define WW 1024
#define BB 8
#define TH 32
#define TW 64
#define HALO_H (TH + 2*PAD)   // 38
#define LDS_W  72             // 4 left halo + 64 + 4 right halo, 16B-aligned
#define NF4    (LDS_W/4)      // 18 float4 per staged row
#define NWAVES 4
#define NTHREADS 256
#define PRO_ROWS 10                    // prologue halo rows 0..9
#define NPOS_PRO (PRO_ROWS * NF4)      // 180
#define GROUP_ROWS 4                   // rows staged per phase
#define NPOS_G (GROUP_ROWS * NF4)      // 72
#define NPHASE 8                       // 32 output rows / 4 waves

#define NIN ((HH - 2*PAD) * (WW - 2*PAD))
#define OUT_SCALE (1.0 / (49.0 * (double)BB * (double)HH * (double)WW))
#define C0 ((float)(48.0 * (double)BB * (double)NIN * OUT_SCALE))
#define NEG_SCALE ((float)(-0.1 * OUT_SCALE))

// keep a value pinned in a VGPR (defeat LDS-load rematerialization)
#define KEEP(v) asm("" : "+v"(v))

static __device__ __forceinline__ f32x2 mk2(float a, float b){ f32x2 r; r.x=a; r.y=b; return r; }
static __device__ __forceinline__ f32x2 sp2(float a){ f32x2 r; r.x=a; r.y=a; return r; }
static __device__ __forceinline__ f32x2 fma2(f32x2 a, f32x2 b, f32x2 c){
    return __builtin_elementwise_fma(a, b, c);
}

// Two offsets at once (compiler-lowered f32x2; verified exact, absmax 0).
//   t^2 = s*(s*A - 2*dx*dy), s=rsq(ax*ay), A=dx^2*ay+dy^2*ax, a*=0.81+d*^2
//   w1/(0.1+t1^2)+w2/(0.1+t2^2) = rcp(b1*b2)*(w1*b2+w2*b1);  INTERIOR: w==2
template<bool INTERIOR>
static __device__ __forceinline__ void pair2(f32x2 nx, f32x2 ny, f32x2 cx2, f32x2 cy2,
                                             f32x2 w2, float& acc)
{
    f32x2 dx  = nx - cx2;
    f32x2 dy  = ny - cy2;
    f32x2 dx2 = dx * dx;
    f32x2 dy2 = dy * dy;
    f32x2 ax  = dx2 + sp2(0.81f);
    f32x2 ay  = dy2 + sp2(0.81f);
    f32x2 P   = ax * ay;
    f32x2 s; s.x = __builtin_amdgcn_rsqf(P.x); s.y = __builtin_amdgcn_rsqf(P.y);
    f32x2 A   = fma2(dx2, ay, dy2 * ax);
    f32x2 h   = dx * dy;
    f32x2 inner = fma2(s, A, h * sp2(-2.0f));
    f32x2 t2  = s * inner;
    f32x2 den = t2 + sp2(0.1f);
    float ip  = __builtin_amdgcn_rcpf(den.x * den.y);
    float cross;
    if constexpr (INTERIOR) cross = den.x + den.y;
    else                    cross = fmaf(w2.x, den.y, w2.y * den.x);
    acc = fmaf(ip, cross, acc);
}

// stage one float4 position (absolute halo row r, float4 col c4) - load+avg+write
static __device__ __forceinline__ void stage_pos(
    float (&sIx)[HALO_H][LDS_W], float (&sIy)[HALO_H][LDS_W],
    const float* __restrict__ xb, const float* __restrict__ yb,
    int tile_i, int tile_j, int r, int c4)
{
    const size_t PLANE = (size_t)HH * WW;
    int gi  = tile_i - PAD + r;
    int gj0 = tile_j - 4 + 4 * c4;
    f32x4 vx = {0.0f, 0.0f, 0.0f, 0.0f};
    f32x4 vy = {0.0f, 0.0f, 0.0f, 0.0f};
    if ((unsigned)gi < (unsigned)HH && (unsigned)gj0 < (unsigned)WW) {
        const float* px = xb + (size_t)gi * WW + gj0;
        f32x4 a0 = *(const f32x4*)(px);
        f32x4 a1 = *(const f32x4*)(px + PLANE);
        f32x4 a2 = *(const f32x4*)(px + 2 * PLANE);
        vx = (a0 + a1 + a2) * (1.0f / 3.0f);
        const float* py = yb + (size_t)gi * WW + gj0;
        f32x4 b0 = *(const f32x4*)(py);
        f32x4 b1 = *(const f32x4*)(py + PLANE);
        f32x4 b2 = *(const f32x4*)(py + 2 * PLANE);
        vy = (b0 + b1 + b2) * (1.0f / 3.0f);
    }
    *(f32x4*)&sIx[r][4 * c4] = vx;
    *(f32x4*)&sIy[r][4 * c4] = vy;
}

// 8-phase pipeline: phase p stages halo rows 10+4p..13+4p (for phase p+1)
// while computing output row 4p+wv (needs halo rows <= 4p+9, staged by p-1).
template<bool INTERIOR>
static __device__ __forceinline__ float run_phases(
    float (&sIx)[HALO_H][LDS_W], float (&sIy)[HALO_H][LDS_W],
    const float* __restrict__ xb, const float* __restrict__ yb,
    int tile_i, int tile_j, int tx, int wv, int tid)
{
    const size_t PLANE = (size_t)HH * WW;

    float cO3 = 0.0f;
    f32x2 cP0 = {}, cP1 = {}, cP2 = {}, cP3 = {};
    if constexpr (!INTERIOR) {
        float cO[7];
        const int gj = tile_j + tx;
        #pragma unroll
        for (int d = 0; d < 7; ++d) {
            int nj = gj + d - 3;
            cO[d] = (nj >= PAD && nj < WW - PAD) ? 1.0f : 0.0f;
        }
        cP0 = mk2(cO[0], cO[1]);
        cP1 = mk2(cO[2], cO[3]);
        cP2 = mk2(cO[4], cO[5]);
        cP3 = sp2(cO[6]);
        cO3 = cO[3];
    }

    float acc = 0.0f;

    #pragma unroll 1
    for (int p = 0; p < NPHASE; ++p) {
        // ---- issue next-group global loads (halo rows 10+4p..13+4p) ----
        f32x4 a0{}, a1{}, a2{}, b0{}, b1{}, b2{};
        float mB = 0.0f;
        int hr = 0, cb4 = 0;
        const bool doSt = (p < NPHASE - 1) && (tid < NPOS_G);
        if (doSt) {
            hr  = PRO_ROWS + GROUP_ROWS * p + tid / NF4;
            cb4 = tid - (tid / NF4) * NF4;
            int gi  = tile_i - PAD + hr;
            int gj0 = tile_j - 4 + 4 * cb4;
            bool ok = ((unsigned)gi < (unsigned)HH) && ((unsigned)gj0 < (unsigned)WW);
            size_t off = ok ? ((size_t)gi * WW + gj0) : 0;   // safe addr if OOB
            const float* px = xb + off;
            const float* py = yb + off;
            a0 = *(const f32x4*)(px);
            a1 = *(const f32x4*)(px + PLANE);
            a2 = *(const f32x4*)(px + 2 * PLANE);
            b0 = *(const f32x4*)(py);
            b1 = *(const f32x4*)(py + PLANE);
            b2 = *(const f32x4*)(py + 2 * PLANE);
            mB = ok ? (1.0f / 3.0f) : 0.0f;
        }
        __builtin_amdgcn_sched_barrier(0);   // keep loads issued before compute

        // ---- compute output row R = 4p + wv (halo rows R+3 .. R+6) ----
        {
            const int R  = GROUP_ROWS * p + wv;     // local row 0..31
            const int gi = tile_i + R;

            float wx[4][7], wy[4][7];
            #pragma unroll
            for (int di = 0; di < 4; ++di) {
                #pragma unroll
                for (int d = 0; d < 7; ++d) {
                    float A_ = sIx[R + 3 + di][tx + 1 + d]; KEEP(A_); wx[di][d] = A_;
                    float C_ = sIy[R + 3 + di][tx + 1 + d]; KEEP(C_); wy[di][d] = C_;
                }
            }

            float rin[4] = {};
            f32x2 mc2 = {};
            if constexpr (!INTERIOR) {
                #pragma unroll
                for (int di = 0; di < 4; ++di) {
                    int ni = gi + di;
                    rin[di] = (ni >= PAD && ni < HH - PAD) ? 1.0f : 0.0f;
                }
                mc2 = sp2(rin[0] * cO3);
            }

            const f32x2 cx2 = sp2(wx[0][3]);
            const f32x2 cy2 = sp2(wy[0][3]);

            // di = 0, dj = +1,+2
            pair2<INTERIOR>(mk2(wx[0][4], wx[0][5]), mk2(wy[0][4], wy[0][5]),
                cx2, cy2, INTERIOR ? sp2(0.0f) : fma2(sp2(rin[0]), cP2, mc2), acc);

            // di = 1..3: dj-pair groups A(-3,-2), B(-1,0), C(+1,+2)
            #pragma unroll
            for (int di = 1; di <= 3; ++di) {
                const f32x2 rin2 = sp2(rin[di]);
                pair2<INTERIOR>(mk2(wx[di][0], wx[di][1]), mk2(wy[di][0], wy[di][1]),
                    cx2, cy2, INTERIOR ? sp2(0.0f) : fma2(rin2, cP0, mc2), acc);
                pair2<INTERIOR>(mk2(wx[di][2], wx[di][3]), mk2(wy[di][2], wy[di][3]),
                    cx2, cy2, INTERIOR ? sp2(0.0f) : fma2(rin2, cP1, mc2), acc);
                pair2<INTERIOR>(mk2(wx[di][4], wx[di][5]), mk2(wy[di][4], wy[di][5]),
                    cx2, cy2, INTERIOR ? sp2(0.0f) : fma2(rin2, cP2, mc2), acc);
            }

            // leftovers dj = +3, packed across di: (0,1) and (2,3)
            pair2<INTERIOR>(mk2(wx[0][6], wx[1][6]), mk2(wy[0][6], wy[1][6]),
                cx2, cy2, INTERIOR ? sp2(0.0f) : fma2(mk2(rin[0], rin[1]), cP3, mc2), acc);
            pair2<INTERIOR>(mk2(wx[2][6], wx[3][6]), mk2(wy[2][6], wy[3][6]),
                cx2, cy2, INTERIOR ? sp2(0.0f) : fma2(mk2(rin[2], rin[3]), cP3, mc2), acc);
        }
        __builtin_amdgcn_sched_barrier(0);   // keep landing after compute

        // ---- land loads (vmcnt wait falls HERE), average, write to LDS ----
        if (doSt) {
            f32x4 vx = (a0 + a1 + a2) * mB;
            f32x4 vy = (b0 + b1 + b2) * mB;
            *(f32x4*)&sIx[hr][4 * cb4] = vx;
            *(f32x4*)&sIy[hr][4 * cb4] = vy;
        }
        __syncthreads();
    }

    return acc;
}

__global__ __launch_bounds__(NTHREADS, 4) void ternary_loss_kernel(
    const float* __restrict__ x, const float* __restrict__ y,
    float* __restrict__ out)
{
    __shared__ __align__(16) float sIx[HALO_H][LDS_W];
    __shared__ __align__(16) float sIy[HALO_H][LDS_W];
    __shared__ float wave_sums[NWAVES];

    const int tile_j = blockIdx.x * TW;
    const int tile_i = blockIdx.y * TH;
    const int b      = blockIdx.z;
    const int tx  = threadIdx.x;            // 0..63
    const int wv  = threadIdx.y;            // 0..3
    const int tid = wv * 64 + tx;

    const size_t PLANE = (size_t)HH * WW;
    const float* xb = x + (size_t)b * 3 * PLANE;
    const float* yb = y + (size_t)b * 3 * PLANE;

    // ---- prologue: stage halo rows 0..9 (covers phase-0 compute) ----
    for (int p = tid; p < NPOS_PRO; p += NTHREADS) {
        int r  = p / NF4;
        int c4 = p - r * NF4;
        stage_pos(sIx, sIy, xb, yb, tile_i, tile_j, r, c4);
    }
    __syncthreads();

    // block-uniform interior test (verified exact, absmax 0)
    const bool interior = (tile_i >= PAD) && (tile_i + TH + PAD <= HH - PAD)
                       && (tile_j >= 2*PAD) && (tile_j + TW + PAD <= WW - PAD);

    float acc;
    if (interior)
        acc = 2.0f * run_phases<true >(sIx, sIy, xb, yb, tile_i, tile_j, tx, wv, tid);
    else
        acc =        run_phases<false>(sIx, sIy, xb, yb, tile_i, tile_j, tx, wv, tid);

    // ---- reduction: wave shuffle -> LDS across 4 waves -> one atomic ----
    #pragma unroll
    for (int off = 32; off > 0; off >>= 1)
        acc += __shfl_down(acc, off, 64);
    if (tx == 0) wave_sums[wv] = acc;
    __syncthreads();
    if (tid == 0) {
        float total = (wave_sums[0] + wave_sums[1] + wave_sums[2] + wave_sums[3]) * NEG_SCALE;
        if (blockIdx.x == 0 && blockIdx.y == 0 && blockIdx.z == 0)
            total += C0;                       // analytic  sum(w)*1  term, added once
        atomicAdd(out, total);
    }
}

extern "C" void kernel_launch(void* const* d_in, const int* in_sizes, int n_in,
                              void* d_out, int out_size, void* d_ws, size_t ws_size,
                              hipStream_t stream) {
    const float* x = (const float*)d_in[0];
    const float* y = (const float*)d_in[1];
    float* out = (float*)d_out;

    hipMemsetAsync(out, 0, sizeof(float), stream);

    dim3 grid(WW / TW, HH / TH, BB);   // 16 x 10 x 8 = 1280 blocks
    dim3 block(64, NWAVES, 1);
    ternary_loss_kernel<<<grid, block, 0, stream>>>(x, y, out);
}

// Round 9
// 119.936 us; speedup vs baseline: 1.0032x; 1.0032x over previous
//
#include <hip/hip_runtime.h>

typedef float f32x2 __attribute__((ext_vector_type(2)));
typedef float f32x4 __attribute__((ext_vector_type(4)));

#define PAD 3
#define HH 320
#define WW 1024
#define BB 8
#define TH 32
#define TW 64
#define HALO_H (TH + 2*PAD)   // 38
#define LDS_W  72             // 4 left halo + 64 + 4 right halo, 16B-aligned
#define NF4    (LDS_W/4)      // 18 float4 per staged row
#define NPOS   (HALO_H * NF4) // 684 float4 positions per plane
#define RPW 8                 // rows per wave (4 waves x 8 rows)
#define NWAVES 4
#define NTHREADS 256

#define NIN ((HH - 2*PAD) * (WW - 2*PAD))
#define OUT_SCALE (1.0 / (49.0 * (double)BB * (double)HH * (double)WW))
#define C0 ((float)(48.0 * (double)BB * (double)NIN * OUT_SCALE))
#define NEG_SCALE ((float)(-0.1 * OUT_SCALE))

// keep a value pinned in a VGPR (defeat LDS-load rematerialization)
#define KEEP(v) asm("" : "+v"(v))

static __device__ __forceinline__ f32x2 mk2(float a, float b){ f32x2 r; r.x=a; r.y=b; return r; }
static __device__ __forceinline__ f32x2 sp2(float a){ f32x2 r; r.x=a; r.y=a; return r; }
static __device__ __forceinline__ f32x2 fma2(f32x2 a, f32x2 b, f32x2 c){
    return __builtin_elementwise_fma(a, b, c);
}

// DEN phase: den = 0.1 + t^2 for two offsets, one independent chain.
//   t^2 = s*(s*A - 2*dx*dy), s=rsq(ax*ay), A=dx^2*ay+dy^2*ax, a*=0.81+d*^2
static __device__ __forceinline__ f32x2 den2(f32x2 nx, f32x2 ny, f32x2 cx2, f32x2 cy2)
{
    f32x2 dx  = nx - cx2;
    f32x2 dy  = ny - cy2;
    f32x2 dx2 = dx * dx;
    f32x2 dy2 = dy * dy;
    f32x2 ax  = dx2 + sp2(0.81f);
    f32x2 ay  = dy2 + sp2(0.81f);
    f32x2 P   = ax * ay;
    f32x2 s; s.x = __builtin_amdgcn_rsqf(P.x); s.y = __builtin_amdgcn_rsqf(P.y);
    f32x2 A   = fma2(dx2, ay, dy2 * ax);
    f32x2 h   = dx * dy;
    f32x2 inner = fma2(s, A, h * sp2(-2.0f));
    return fma2(s, inner, sp2(0.1f));          // den = t2 + 0.1
}

// COMBINE phase: 4 offsets (two den-pairs) share ONE rcp:
//   sum w_i/den_i = rcp(Pa*Pb) * (ca*Pb + cb*Pa),
//   Pa = a.x*a.y, ca = wa.x*a.y + wa.y*a.x  (INTERIOR: ca = a.x + a.y, w==2
//   applied once at the end).
template<bool INTERIOR>
static __device__ __forceinline__ void comb4(f32x2 a, f32x2 b, f32x2 wa, f32x2 wb,
                                             float& acc)
{
    float Pa = a.x * a.y;
    float Pb = b.x * b.y;
    float ca, cb;
    if constexpr (INTERIOR) { ca = a.x + a.y;                 cb = b.x + b.y; }
    else { ca = fmaf(wa.x, a.y, wa.y * a.x);  cb = fmaf(wb.x, b.y, wb.y * b.x); }
    float Q = Pa * Pb;
    float C = fmaf(ca, Pb, cb * Pa);
    acc = fmaf(C, __builtin_amdgcn_rcpf(Q), acc);
}

template<bool INTERIOR>
static __device__ __forceinline__ float compute_rows(
    const float (&sIx)[HALO_H][LDS_W], const float (&sIy)[HALO_H][LDS_W],
    int tile_i, int tile_j, int tx, int wv)
{
    float cO3 = 0.0f;
    f32x2 cP0 = {}, cP1 = {}, cP2 = {}, cP3 = {};
    if constexpr (!INTERIOR) {
        float cO[7];
        const int gj = tile_j + tx;
        #pragma unroll
        for (int d = 0; d < 7; ++d) {
            int nj = gj + d - 3;
            cO[d] = (nj >= PAD && nj < WW - PAD) ? 1.0f : 0.0f;
        }
        cP0 = mk2(cO[0], cO[1]);
        cP1 = mk2(cO[2], cO[3]);
        cP2 = mk2(cO[4], cO[5]);
        cP3 = sp2(cO[6]);
        cO3 = cO[3];
    }

    const int li0 = wv * RPW;

    // rolling 4-row register window
    float wx[4][7], wy[4][7];
    #pragma unroll
    for (int r = 0; r < 3; ++r) {
        #pragma unroll
        for (int d = 0; d < 7; ++d) {
            float a = sIx[li0 + 3 + r][tx + 1 + d]; KEEP(a); wx[r][d] = a;
            float c = sIy[li0 + 3 + r][tx + 1 + d]; KEEP(c); wy[r][d] = c;
        }
    }

    float acc = 0.0f;

    #pragma unroll 1
    for (int io = 0; io < RPW / 4; ++io) {
        #pragma unroll
        for (int iu = 0; iu < 4; ++iu) {
            const int li = li0 + io * 4 + iu;
            const int gi = tile_i + li;
            const int sn = (iu + 3) & 3;
            #pragma unroll
            for (int d = 0; d < 7; ++d) {
                float a = sIx[li + 6][tx + 1 + d]; KEEP(a); wx[sn][d] = a;
                float c = sIy[li + 6][tx + 1 + d]; KEEP(c); wy[sn][d] = c;
            }

            float rin[4] = {};
            f32x2 mc2 = {};
            if constexpr (!INTERIOR) {
                #pragma unroll
                for (int di = 0; di < 4; ++di) {
                    int ni = gi + di;
                    rin[di] = (ni >= PAD && ni < HH - PAD) ? 1.0f : 0.0f;
                }
                mc2 = sp2(rin[0] * cO3);
            }

            const int s0 = iu & 3, s1 = (iu+1)&3, s2 = (iu+2)&3, s3_ = (iu+3)&3;
            const f32x2 cx2 = sp2(wx[s0][3]);
            const f32x2 cy2 = sp2(wy[s0][3]);

            // ---- DEN phase: 12 independent chains (ILP for the trans pipe) ----
            f32x2 d0  = den2(mk2(wx[s0][4], wx[s0][5]), mk2(wy[s0][4], wy[s0][5]), cx2, cy2);
            f32x2 d1  = den2(mk2(wx[s1][0], wx[s1][1]), mk2(wy[s1][0], wy[s1][1]), cx2, cy2);
            f32x2 d2  = den2(mk2(wx[s1][2], wx[s1][3]), mk2(wy[s1][2], wy[s1][3]), cx2, cy2);
            f32x2 d3  = den2(mk2(wx[s1][4], wx[s1][5]), mk2(wy[s1][4], wy[s1][5]), cx2, cy2);
            f32x2 d4  = den2(mk2(wx[s2][0], wx[s2][1]), mk2(wy[s2][0], wy[s2][1]), cx2, cy2);
            f32x2 d5  = den2(mk2(wx[s2][2], wx[s2][3]), mk2(wy[s2][2], wy[s2][3]), cx2, cy2);
            f32x2 d6  = den2(mk2(wx[s2][4], wx[s2][5]), mk2(wy[s2][4], wy[s2][5]), cx2, cy2);
            f32x2 d7  = den2(mk2(wx[s3_][0], wx[s3_][1]), mk2(wy[s3_][0], wy[s3_][1]), cx2, cy2);
            f32x2 d8  = den2(mk2(wx[s3_][2], wx[s3_][3]), mk2(wy[s3_][2], wy[s3_][3]), cx2, cy2);
            f32x2 d9  = den2(mk2(wx[s3_][4], wx[s3_][5]), mk2(wy[s3_][4], wy[s3_][5]), cx2, cy2);
            f32x2 d10 = den2(mk2(wx[s0][6], wx[s1][6]),  mk2(wy[s0][6], wy[s1][6]),  cx2, cy2);
            f32x2 d11 = den2(mk2(wx[s2][6], wx[s3_][6]), mk2(wy[s2][6], wy[s3_][6]), cx2, cy2);

            // ---- weights (border blocks only; DCE'd on interior path) ----
            f32x2 W0 = {}, W1 = {}, W2 = {}, W3 = {}, W4 = {}, W5 = {};
            f32x2 W6 = {}, W7 = {}, W8 = {}, W9 = {}, W10 = {}, W11 = {};
            if constexpr (!INTERIOR) {
                const f32x2 r1v = sp2(rin[1]), r2v = sp2(rin[2]), r3v = sp2(rin[3]);
                W0  = fma2(sp2(rin[0]), cP2, mc2);
                W1  = fma2(r1v, cP0, mc2);
                W2  = fma2(r1v, cP1, mc2);
                W3  = fma2(r1v, cP2, mc2);
                W4  = fma2(r2v, cP0, mc2);
                W5  = fma2(r2v, cP1, mc2);
                W6  = fma2(r2v, cP2, mc2);
                W7  = fma2(r3v, cP0, mc2);
                W8  = fma2(r3v, cP1, mc2);
                W9  = fma2(r3v, cP2, mc2);
                W10 = fma2(mk2(rin[0], rin[1]), cP3, mc2);
                W11 = fma2(mk2(rin[2], rin[3]), cP3, mc2);
            }

            // ---- COMBINE phase: 6 rcp for 24 offsets ----
            comb4<INTERIOR>(d0,  d1,  W0,  W1,  acc);
            comb4<INTERIOR>(d2,  d3,  W2,  W3,  acc);
            comb4<INTERIOR>(d4,  d5,  W4,  W5,  acc);
            comb4<INTERIOR>(d6,  d7,  W6,  W7,  acc);
            comb4<INTERIOR>(d8,  d9,  W8,  W9,  acc);
            comb4<INTERIOR>(d10, d11, W10, W11, acc);
        }
    }

    return acc;
}

__global__ __launch_bounds__(NTHREADS, 4) void ternary_loss_kernel(
    const float* __restrict__ x, const float* __restrict__ y,
    float* __restrict__ out)
{
    __shared__ __align__(16) float sIx[HALO_H][LDS_W];
    __shared__ __align__(16) float sIy[HALO_H][LDS_W];
    __shared__ float wave_sums[NWAVES];

    const int tile_j = blockIdx.x * TW;
    const int tile_i = blockIdx.y * TH;
    const int b      = blockIdx.z;
    const int tx  = threadIdx.x;            // 0..63
    const int wv  = threadIdx.y;            // 0..3
    const int tid = wv * 64 + tx;

    const size_t PLANE = (size_t)HH * WW;
    const float* xb = x + (size_t)b * 3 * PLANE;
    const float* yb = y + (size_t)b * 3 * PLANE;

    // ---- stage intensity halo tile into LDS with aligned float4 loads ----
    for (int p = tid; p < NPOS; p += NTHREADS) {
        int r  = p / NF4;
        int c4 = p - r * NF4;
        int gi  = tile_i - PAD + r;
        int gj0 = tile_j - 4 + 4 * c4;
        f32x4 vx = {0.0f, 0.0f, 0.0f, 0.0f};
        f32x4 vy = {0.0f, 0.0f, 0.0f, 0.0f};
        if ((unsigned)gi < (unsigned)HH && (unsigned)gj0 < (unsigned)WW) {
            const float* px = xb + (size_t)gi * WW + gj0;
            f32x4 a0 = *(const f32x4*)(px);
            f32x4 a1 = *(const f32x4*)(px + PLANE);
            f32x4 a2 = *(const f32x4*)(px + 2 * PLANE);
            vx = (a0 + a1 + a2) * (1.0f / 3.0f);
            const float* py = yb + (size_t)gi * WW + gj0;
            f32x4 b0 = *(const f32x4*)(py);
            f32x4 b1 = *(const f32x4*)(py + PLANE);
            f32x4 b2 = *(const f32x4*)(py + 2 * PLANE);
            vy = (b0 + b1 + b2) * (1.0f / 3.0f);
        }
        *(f32x4*)&sIx[r][4 * c4] = vx;
        *(f32x4*)&sIy[r][4 * c4] = vy;
    }
    __syncthreads();

    // block-uniform interior test (verified exact, absmax 0)
    const bool interior = (tile_i >= PAD) && (tile_i + TH + PAD <= HH - PAD)
                       && (tile_j >= 2*PAD) && (tile_j + TW + PAD <= WW - PAD);

    float acc;
    if (interior) acc = 2.0f * compute_rows<true >(sIx, sIy, tile_i, tile_j, tx, wv);
    else          acc =        compute_rows<false>(sIx, sIy, tile_i, tile_j, tx, wv);

    // ---- reduction: wave shuffle -> LDS across 4 waves -> one atomic ----
    #pragma unroll
    for (int off = 32; off > 0; off >>= 1)
        acc += __shfl_down(acc, off, 64);
    if (tx == 0) wave_sums[wv] = acc;
    __syncthreads();
    if (tid == 0) {
        float total = (wave_sums[0] + wave_sums[1] + wave_sums[2] + wave_sums[3]) * NEG_SCALE;
        if (blockIdx.x == 0 && blockIdx.y == 0 && blockIdx.z == 0)
            total += C0;                       // analytic  sum(w)*1  term, added once
        atomicAdd(out, total);
    }
}

extern "C" void kernel_launch(void* const* d_in, const int* in_sizes, int n_in,
                              void* d_out, int out_size, void* d_ws, size_t ws_size,
                              hipStream_t stream) {
    const float* x = (const float*)d_in[0];
    const float* y = (const float*)d_in[1];
    float* out = (float*)d_out;

    hipMemsetAsync(out, 0, sizeof(float), stream);

    dim3 grid(WW / TW, HH / TH, BB);   // 16 x 10 x 8 = 1280 blocks
    dim3 block(64, NWAVES, 1);
    ternary_loss_kernel<<<grid, block, 0, stream>>>(x, y, out);
}